// Round 16
// baseline (163.496 us; speedup 1.0000x reference)
//
#include <hip/hip_runtime.h>

typedef _Float16 h16;
typedef _Float16 h16x4 __attribute__((ext_vector_type(4)));
typedef _Float16 h16x8 __attribute__((ext_vector_type(8)));
typedef __fp16 fp16x2 __attribute__((ext_vector_type(2)));   // cvt_pkrtz native type
typedef float f32x4 __attribute__((ext_vector_type(4)));

#define SEQ 2048
#define RSTRIDE 8192   // b*h*d = 4*16*128
#define QTILE 128
#define NQT (SEQ / QTILE)   // 16
#define KBLK 64
#define KPAD 136       // K LDS row stride (halves): b128 r/w conflict-free in 8-lane groups
#define VPAD 76        // V LDS row stride (halves): 152B/row -> 6-bank step, bijective over 16 lanes
#define DEFER_THR 8.0f

static __device__ __forceinline__ h16x8 pack8(f32x4 a, f32x4 b) {
    union { fp16x2 h2[4]; h16x8 h8; } u;
    u.h2[0] = __builtin_amdgcn_cvt_pkrtz(a[0], a[1]);
    u.h2[1] = __builtin_amdgcn_cvt_pkrtz(a[2], a[3]);
    u.h2[2] = __builtin_amdgcn_cvt_pkrtz(b[0], b[1]);
    u.h2[3] = __builtin_amdgcn_cvt_pkrtz(b[2], b[3]);
    return u.h8;
}

static __device__ __forceinline__ h16x4 pack4(float x0, float x1, float x2, float x3) {
    union { fp16x2 h2[2]; h16x4 h4; } u;
    u.h2[0] = __builtin_amdgcn_cvt_pkrtz(x0, x1);
    u.h2[1] = __builtin_amdgcn_cvt_pkrtz(x2, x3);
    return u.h4;
}

// drain ONLY LDS ops before the barrier; register-destined global loads stay in flight
static __device__ __forceinline__ void barrier_lgkm() {
    asm volatile("s_waitcnt lgkmcnt(0)" ::: "memory");
    __builtin_amdgcn_s_barrier();
}

__global__ __launch_bounds__(256, 2)
void fa_fwd_kernel(const float* __restrict__ Qg, const float* __restrict__ Kg,
                   const float* __restrict__ Vg, float* __restrict__ Out)
{
    // 73.7 KB per block -> exactly 2 independent blocks per CU (separate barriers
    // -> phase drift -> MFMA/VALU/LDS overlap across blocks)
    __shared__ __attribute__((aligned(16))) h16 Kl[2][KBLK * KPAD];   // [key][d]
    __shared__ __attribute__((aligned(16))) h16 Vt[2][128 * VPAD];    // [d][key], linear

    // decode: XCD = lin&7 owns bh {8*(lin&7) .. +7}; bijective
    const int lin = (int)blockIdx.x;              // 0..511
    const int bx  = (lin >> 3) & 7;               // 0..7, pairs (bx, 15-bx)
    const int bh  = 8 * (lin & 7) + (lin >> 6);   // 0..63
    const int tid  = threadIdx.x;   // 0..255 (4 waves)
    const int wave = tid >> 6;
    const int lane = tid & 63;
    const int lg   = lane >> 4;
    const int lc   = lane & 15;
    const size_t bhoff = (size_t)bh * 128;
    const float NEGINF = -__builtin_inff();
    const float SL = 0.08838834764831845f * 1.4426950408889634f;  // (1/sqrt(128))*log2(e)

    // ---- K staging geometry (256 thr): row = tid>>4 + 16*it (it 0..3), 8 floats each
    const int krow = tid >> 4;            // 0..15
    const int kd0  = (tid & 15) * 8;
    const float* kbase = Kg + (size_t)krow * RSTRIDE + bhoff + kd0;
    const int kwoff = krow * KPAD + kd0;

    // ---- V staging geometry (256 thr): key-group = tid&15, d-block = tid>>4
    // b64 LDS writes: bank = 38*(8*db+e) + 2*l over 16-lane group -> conflict-free
    const int vkey0 = 4 * (tid & 15);     // 0..60
    const int vd0   = 8 * (tid >> 4);     // 0..120
    const float* vbase = Vg + (size_t)vkey0 * RSTRIDE + bhoff + vd0;

    // ---- per-lane LDS fragment bases
    const int kfoff = lc * KPAD + lg * 8;   // + kt*16*KPAD + dk*32
    const int vfoff = lc * VPAD + 4 * lg;   // + dt*16*VPAD + 32u + 16s  (all immediates)

    // ones B-fragment for the P.1 row-sum MFMA
    const h16x8 vones = h16x8{(h16)1.f,(h16)1.f,(h16)1.f,(h16)1.f,
                              (h16)1.f,(h16)1.f,(h16)1.f,(h16)1.f};

    f32x4 kra[4], krb[4], vra[8];   // prefetch registers (T14)

    for (int half = 0; half < 2; ++half) {
        const int qt = half ? (NQT - 1 - bx) : bx;
        const int q0 = qt * QTILE;
        const int wbase = q0 + wave * 32;    // wave's 32 q-rows (2 fused strips)

        // ---- Q fragments, pre-scaled
        h16x8 qf[2][4];
#pragma unroll
        for (int s2 = 0; s2 < 2; ++s2) {
            const int qrow = wbase + s2 * 16 + lc;
            const float* qp = Qg + (size_t)qrow * RSTRIDE + bhoff + lg * 8;
#pragma unroll
            for (int dk = 0; dk < 4; ++dk) {
                f32x4 a = *(const f32x4*)(qp + dk * 32);
                f32x4 b2 = *(const f32x4*)(qp + dk * 32 + 4);
#pragma unroll
                for (int j = 0; j < 4; ++j) { a[j] *= SL; b2[j] *= SL; }
                qf[s2][dk] = pack8(a, b2);
            }
        }

        f32x4 o[2][8];
#pragma unroll
        for (int s2 = 0; s2 < 2; ++s2)
#pragma unroll
            for (int dt = 0; dt < 8; ++dt) o[s2][dt] = f32x4{0.f, 0.f, 0.f, 0.f};
        float mreg[2] = {NEGINF, NEGINF};
        f32x4 lacc[2];                       // row-sums via ones-MFMA
        lacc[0] = f32x4{0.f, 0.f, 0.f, 0.f};
        lacc[1] = f32x4{0.f, 0.f, 0.f, 0.f};

        const int nkv = 2 * (qt + 1);

        // ---- prologue: load t0 -> regs
#pragma unroll
        for (int it = 0; it < 4; ++it) {
            const float* gp = kbase + (size_t)(16 * it) * RSTRIDE;
            kra[it] = *(const f32x4*)gp;
            krb[it] = *(const f32x4*)(gp + 4);
        }
#pragma unroll
        for (int j = 0; j < 4; ++j) {
            const float* gp = vbase + (size_t)j * RSTRIDE;
            vra[2 * j]     = *(const f32x4*)gp;
            vra[2 * j + 1] = *(const f32x4*)(gp + 4);
        }
        barrier_lgkm();   // previous half's LDS reads done before overwrite
        {
            h16* kw = &Kl[0][kwoff];
#pragma unroll
            for (int it = 0; it < 4; ++it)
                *(h16x8*)(kw + it * 16 * KPAD) = pack8(kra[it], krb[it]);
#pragma unroll
            for (int e = 0; e < 8; ++e)
                *(h16x4*)&Vt[0][(vd0 + e) * VPAD + vkey0] =
                    pack4(vra[(e >> 2)][e & 3],     vra[2 + (e >> 2)][e & 3],
                          vra[4 + (e >> 2)][e & 3], vra[6 + (e >> 2)][e & 3]);
        }
        if (nkv > 1) {
            const size_t toff = (size_t)KBLK * RSTRIDE;
#pragma unroll
            for (int it = 0; it < 4; ++it) {
                const float* gp = kbase + toff + (size_t)(16 * it) * RSTRIDE;
                kra[it] = *(const f32x4*)gp;
                krb[it] = *(const f32x4*)(gp + 4);
            }
#pragma unroll
            for (int j = 0; j < 4; ++j) {
                const float* gp = vbase + toff + (size_t)j * RSTRIDE;
                vra[2 * j]     = *(const f32x4*)gp;
                vra[2 * j + 1] = *(const f32x4*)(gp + 4);
            }
        }
        barrier_lgkm();   // buf0 visible; t1 loads stay in flight

        for (int t = 0; t < nkv; ++t) {
            const int kv0 = t * KBLK;
            const int cb = t & 1;
            const bool doc = (kv0 <= wbase + 31);   // wave-uniform

            h16x8 pa[2][2];

            // ---- phase 1: QK + softmax (ds_reads start at stage head)
            if (doc) {
                const h16* Kfb = &Kl[cb][kfoff];
                f32x4 sacc[2][4];
#pragma unroll
                for (int s2 = 0; s2 < 2; ++s2)
#pragma unroll
                    for (int kt = 0; kt < 4; ++kt) sacc[s2][kt] = f32x4{0.f, 0.f, 0.f, 0.f};
#pragma unroll
                for (int kt = 0; kt < 4; ++kt) {
#pragma unroll
                    for (int dk = 0; dk < 4; ++dk) {
                        h16x8 a = *(const h16x8*)(Kfb + kt * 16 * KPAD + dk * 32);
                        sacc[0][kt] = __builtin_amdgcn_mfma_f32_16x16x32_f16(a, qf[0][dk], sacc[0][kt], 0, 0, 0);
                        sacc[1][kt] = __builtin_amdgcn_mfma_f32_16x16x32_f16(a, qf[1][dk], sacc[1][kt], 0, 0, 0);
                    }
                }

                float vmax[2];
                if (kv0 + 63 <= wbase) {       // interior for both strips
#pragma unroll
                    for (int s2 = 0; s2 < 2; ++s2) {
                        const float a0 = fmaxf(fmaxf(sacc[s2][0][0], sacc[s2][0][1]), sacc[s2][0][2]);
                        const float a1 = fmaxf(fmaxf(sacc[s2][0][3], sacc[s2][1][0]), sacc[s2][1][1]);
                        const float a2 = fmaxf(fmaxf(sacc[s2][1][2], sacc[s2][1][3]), sacc[s2][2][0]);
                        const float a3 = fmaxf(fmaxf(sacc[s2][2][1], sacc[s2][2][2]), sacc[s2][2][3]);
                        const float a4 = fmaxf(fmaxf(sacc[s2][3][0], sacc[s2][3][1]), sacc[s2][3][2]);
                        const float b0 = fmaxf(fmaxf(a0, a1), a2);
                        const float b1 = fmaxf(fmaxf(a3, a4), sacc[s2][3][3]);
                        vmax[s2] = fmaxf(b0, b1);
                    }
                } else {
#pragma unroll
                    for (int s2 = 0; s2 < 2; ++s2) {
                        vmax[s2] = NEGINF;
                        const int qrow = wbase + s2 * 16 + lc;
#pragma unroll
                        for (int kt = 0; kt < 4; ++kt)
#pragma unroll
                            for (int r = 0; r < 4; ++r) {
                                const int key = kv0 + 16 * kt + 4 * lg + r;
                                float sv = (key <= qrow) ? sacc[s2][kt][r] : NEGINF;
                                sacc[s2][kt][r] = sv;
                                vmax[s2] = fmaxf(vmax[s2], sv);
                            }
                    }
                }

#pragma unroll
                for (int s2 = 0; s2 < 2; ++s2) {
                    if (__any(vmax[s2] > mreg[s2] + DEFER_THR)) {
                        float rmax = fmaxf(vmax[s2], __shfl_xor(vmax[s2], 16, 64));
                        rmax = fmaxf(rmax, __shfl_xor(rmax, 32, 64));
                        const float mnew  = fmaxf(mreg[s2], rmax);
                        const float alpha = __builtin_amdgcn_exp2f(mreg[s2] - mnew);
                        mreg[s2] = mnew;
#pragma unroll
                        for (int r = 0; r < 4; ++r) {
                            const float ar = __shfl(alpha, 4 * lg + r, 64);
                            lacc[s2][r] *= ar;
#pragma unroll
                            for (int dt = 0; dt < 8; ++dt) o[s2][dt][r] *= ar;
                        }
                    }
#pragma unroll
                    for (int kt = 0; kt < 4; ++kt)
#pragma unroll
                        for (int r = 0; r < 4; ++r)
                            sacc[s2][kt][r] = __builtin_amdgcn_exp2f(sacc[s2][kt][r] - mreg[s2]);
#pragma unroll
                    for (int u = 0; u < 2; ++u)
                        pa[s2][u] = pack8(sacc[s2][2 * u], sacc[s2][2 * u + 1]);
                    lacc[s2] = __builtin_amdgcn_mfma_f32_16x16x32_f16(pa[s2][0], vones, lacc[s2], 0, 0, 0);
                    lacc[s2] = __builtin_amdgcn_mfma_f32_16x16x32_f16(pa[s2][1], vones, lacc[s2], 0, 0, 0);
                }
            }

            // ---- phase 2: staging writes t+1 (hide under PV below)
            if (t + 1 < nkv) {
                h16* kw = &Kl[cb ^ 1][kwoff];
#pragma unroll
                for (int it = 0; it < 4; ++it)
                    *(h16x8*)(kw + it * 16 * KPAD) = pack8(kra[it], krb[it]);
#pragma unroll
                for (int e = 0; e < 8; ++e)
                    *(h16x4*)&Vt[cb ^ 1][(vd0 + e) * VPAD + vkey0] =
                        pack4(vra[(e >> 2)][e & 3],     vra[2 + (e >> 2)][e & 3],
                              vra[4 + (e >> 2)][e & 3], vra[6 + (e >> 2)][e & 3]);
            }
            // ---- phase 3: issue t+2 global loads
            if (t + 2 < nkv) {
                const size_t toff = (size_t)(kv0 + 2 * KBLK) * RSTRIDE;
#pragma unroll
                for (int it = 0; it < 4; ++it) {
                    const float* gp = kbase + toff + (size_t)(16 * it) * RSTRIDE;
                    kra[it] = *(const f32x4*)gp;
                    krb[it] = *(const f32x4*)(gp + 4);
                }
#pragma unroll
                for (int j = 0; j < 4; ++j) {
                    const float* gp = vbase + toff + (size_t)j * RSTRIDE;
                    vra[2 * j]     = *(const f32x4*)gp;
                    vra[2 * j + 1] = *(const f32x4*)(gp + 4);
                }
            }

            // ---- phase 4: PV (linear [d][key] reads, conflict-free, pure-imm offsets)
            if (doc) {
                const h16* Vfb = &Vt[cb][vfoff];
#pragma unroll
                for (int dt = 0; dt < 8; ++dt) {
#pragma unroll
                    for (int u = 0; u < 2; ++u) {
                        union { h16x8 v8; h16x4 v4[2]; } bv;
                        bv.v4[0] = *(const h16x4*)(Vfb + dt * 16 * VPAD + 32 * u);
                        bv.v4[1] = *(const h16x4*)(Vfb + dt * 16 * VPAD + 32 * u + 16);
                        o[0][dt] = __builtin_amdgcn_mfma_f32_16x16x32_f16(pa[0][u], bv.v8, o[0][dt], 0, 0, 0);
                        o[1][dt] = __builtin_amdgcn_mfma_f32_16x16x32_f16(pa[1][u], bv.v8, o[1][dt], 0, 0, 0);
                    }
                }
            }
            barrier_lgkm();   // per-block barrier; other block on the CU drifts freely
        } // kv tiles

        // ---- epilogue: lacc[s2][r] is the full row-sum for q = wbase+16s2+4lg+r
#pragma unroll
        for (int s2 = 0; s2 < 2; ++s2) {
#pragma unroll
            for (int r = 0; r < 4; ++r) {
                const float inv = 1.0f / lacc[s2][r];
                const int qrow  = wbase + s2 * 16 + 4 * lg + r;
                float* op = Out + (size_t)qrow * RSTRIDE + bhoff + lc;
#pragma unroll
                for (int dt = 0; dt < 8; ++dt) op[dt * 16] = o[s2][dt][r] * inv;
            }
        }
    } // half
}

extern "C" void kernel_launch(void* const* d_in, const int* in_sizes, int n_in,
                              void* d_out, int out_size, void* d_ws, size_t ws_size,
                              hipStream_t stream) {
    (void)in_sizes; (void)n_in; (void)out_size; (void)d_ws; (void)ws_size;
    const float* Q = (const float*)d_in[0];
    const float* K = (const float*)d_in[1];
    const float* V = (const float*)d_in[2];
    float* O = (float*)d_out;
    fa_fwd_kernel<<<dim3(512), 256, 0, stream>>>(Q, K, V, O);
}

// Round 17
// 104.094 us; speedup vs baseline: 1.5707x; 1.5707x over previous
//
#include <hip/hip_runtime.h>

typedef _Float16 h16;
typedef _Float16 h16x4 __attribute__((ext_vector_type(4)));
typedef _Float16 h16x8 __attribute__((ext_vector_type(8)));
typedef __fp16 fp16x2 __attribute__((ext_vector_type(2)));   // cvt_pkrtz native type
typedef float f32x4 __attribute__((ext_vector_type(4)));

#define SEQ 2048
#define RSTRIDE 8192   // b*h*d = 4*16*128
#define QTILE 256
#define NQT (SEQ / QTILE)   // 8
#define KBLK 64
#define KPAD 136       // K LDS row stride (halves): b128 r/w conflict-free in 8-lane groups
#define VPAD 76        // V LDS row stride (halves): 6-bank row step, bijective over 16 lanes
#define DEFER_THR 8.0f

static __device__ __forceinline__ h16x8 pack8(f32x4 a, f32x4 b) {
    union { fp16x2 h2[4]; h16x8 h8; } u;
    u.h2[0] = __builtin_amdgcn_cvt_pkrtz(a[0], a[1]);
    u.h2[1] = __builtin_amdgcn_cvt_pkrtz(a[2], a[3]);
    u.h2[2] = __builtin_amdgcn_cvt_pkrtz(b[0], b[1]);
    u.h2[3] = __builtin_amdgcn_cvt_pkrtz(b[2], b[3]);
    return u.h8;
}

static __device__ __forceinline__ h16x4 pack4(float x0, float x1, float x2, float x3) {
    union { fp16x2 h2[2]; h16x4 h4; } u;
    u.h2[0] = __builtin_amdgcn_cvt_pkrtz(x0, x1);
    u.h2[1] = __builtin_amdgcn_cvt_pkrtz(x2, x3);
    return u.h4;
}

// drain ONLY LDS ops before the barrier; register-destined global loads stay in flight
static __device__ __forceinline__ void barrier_lgkm() {
    asm volatile("s_waitcnt lgkmcnt(0)" ::: "memory");
    __builtin_amdgcn_s_barrier();
}

__global__ __launch_bounds__(512, 2)
void fa_fwd_kernel(const float* __restrict__ Qg, const float* __restrict__ Kg,
                   const float* __restrict__ Vg, float* __restrict__ Out)
{
    // 4-deep buffer ring (144 KB): ONE barrier per TWO KV tiles.
    // Pair (t,t+1): reads touch bufs {t,t+1}&3, writes {t+2,t+3}&3 -> disjoint for
    // any intra-pair wave drift; written bufs' last readers finished pre-barrier.
    __shared__ __attribute__((aligned(16))) h16 Kl[4][KBLK * KPAD];   // [key][d]
    __shared__ __attribute__((aligned(16))) h16 Vt[4][128 * VPAD];    // [d][key], linear

    // XCD-aware remap (256 blocks, 1/CU): XCD x owns bh in {8x..8x+7}
    const int lin = (int)blockIdx.x + 4 * (int)blockIdx.y;   // hw XCD = lin % 8
    const int bx  = (lin >> 3) & 3;               // 0..3, pairs (bx, 7-bx)
    const int bh  = 8 * (lin & 7) + (lin >> 5);   // 0..63
    const int tid  = threadIdx.x;   // 0..511 (8 waves)
    const int wave = tid >> 6;
    const int lane = tid & 63;
    const int lg   = lane >> 4;
    const int lc   = lane & 15;
    const size_t bhoff = (size_t)bh * 128;
    const float NEGINF = -__builtin_inff();
    const float SL = 0.08838834764831845f * 1.4426950408889634f;  // (1/sqrt(128))*log2(e)

    // ---- K staging geometry
    const int krow = tid >> 4;            // 0..31 (+32*it)
    const int kd0  = (tid & 15) * 8;
    const float* kbase = Kg + (size_t)krow * RSTRIDE + bhoff + kd0;
    const int kwoff = krow * KPAD + kd0;

    // ---- V staging geometry: key-group XOR-permuted so b64 LDS writes are conflict-free
    const int vkg   = ((tid >> 5) ^ ((tid & 31) >> 2)) & 15;  // key-group 0..15
    const int vkey0 = 4 * vkg;
    const int vd0   = 4 * (tid & 31);     // 0..124
    const float* vbase = Vg + (size_t)vkey0 * RSTRIDE + bhoff + vd0;

    // ---- per-lane LDS fragment bases
    const int kfoff = lc * KPAD + lg * 8;   // + kt*16*KPAD + dk*32
    const int vfoff = lc * VPAD + 4 * lg;   // + dt*16*VPAD + 32u + 16s  (all immediates)

    // ones B-fragment for the P.1 row-sum MFMA
    const h16x8 vones = h16x8{(h16)1.f,(h16)1.f,(h16)1.f,(h16)1.f,
                              (h16)1.f,(h16)1.f,(h16)1.f,(h16)1.f};

    f32x4 kra[2], krb[2], vra[4];   // single-tile prefetch registers (T14)

    for (int half = 0; half < 2; ++half) {
        const int qt = half ? (NQT - 1 - bx) : bx;
        const int q0 = qt * QTILE;
        const int wbase = q0 + wave * 32;    // wave's 32 q-rows (2 fused strips)

        // ---- Q fragments, pre-scaled
        h16x8 qf[2][4];
#pragma unroll
        for (int s2 = 0; s2 < 2; ++s2) {
            const int qrow = wbase + s2 * 16 + lc;
            const float* qp = Qg + (size_t)qrow * RSTRIDE + bhoff + lg * 8;
#pragma unroll
            for (int dk = 0; dk < 4; ++dk) {
                f32x4 a = *(const f32x4*)(qp + dk * 32);
                f32x4 b2 = *(const f32x4*)(qp + dk * 32 + 4);
#pragma unroll
                for (int j = 0; j < 4; ++j) { a[j] *= SL; b2[j] *= SL; }
                qf[s2][dk] = pack8(a, b2);
            }
        }

        f32x4 o[2][8];
#pragma unroll
        for (int s2 = 0; s2 < 2; ++s2)
#pragma unroll
            for (int dt = 0; dt < 8; ++dt) o[s2][dt] = f32x4{0.f, 0.f, 0.f, 0.f};
        float mreg[2] = {NEGINF, NEGINF};
        f32x4 lacc[2];                       // row-sums via ones-MFMA
        lacc[0] = f32x4{0.f, 0.f, 0.f, 0.f};
        lacc[1] = f32x4{0.f, 0.f, 0.f, 0.f};

        const int nkv = 4 * (qt + 1);        // even, >= 4

        // ---- helpers ----
        auto load_tile = [&](int t) {
            const size_t toff = (size_t)(t * KBLK) * RSTRIDE;
#pragma unroll
            for (int it = 0; it < 2; ++it) {
                const float* gp = kbase + toff + (size_t)(32 * it) * RSTRIDE;
                kra[it] = *(const f32x4*)gp;
                krb[it] = *(const f32x4*)(gp + 4);
            }
#pragma unroll
            for (int kk = 0; kk < 4; ++kk)
                vra[kk] = *(const f32x4*)(vbase + toff + (size_t)kk * RSTRIDE);
        };
        auto write_tile = [&](int wb) {
            h16* kw = &Kl[wb][kwoff];
#pragma unroll
            for (int it = 0; it < 2; ++it)
                *(h16x8*)(kw + it * 32 * KPAD) = pack8(kra[it], krb[it]);
#pragma unroll
            for (int e = 0; e < 4; ++e)
                *(h16x4*)&Vt[wb][(vd0 + e) * VPAD + vkey0] =
                    pack4(vra[0][e], vra[1][e], vra[2][e], vra[3][e]);
        };

        // ---- one tile iteration: QK+softmax -> staging write -> prefetch -> PV
        auto tile_iter = [&](int tt, int wt, int lt) {
            const int kv0 = tt * KBLK;
            const int cb = tt & 3;
            const bool doc = (kv0 <= wbase + 31);   // wave-uniform

            h16x8 pa[2][2];

            if (doc) {
                const h16* Kfb = &Kl[cb][kfoff];
                f32x4 sacc[2][4];
#pragma unroll
                for (int s2 = 0; s2 < 2; ++s2)
#pragma unroll
                    for (int kt = 0; kt < 4; ++kt) sacc[s2][kt] = f32x4{0.f, 0.f, 0.f, 0.f};
#pragma unroll
                for (int kt = 0; kt < 4; ++kt) {
#pragma unroll
                    for (int dk = 0; dk < 4; ++dk) {
                        h16x8 a = *(const h16x8*)(Kfb + kt * 16 * KPAD + dk * 32);
                        sacc[0][kt] = __builtin_amdgcn_mfma_f32_16x16x32_f16(a, qf[0][dk], sacc[0][kt], 0, 0, 0);
                        sacc[1][kt] = __builtin_amdgcn_mfma_f32_16x16x32_f16(a, qf[1][dk], sacc[1][kt], 0, 0, 0);
                    }
                }

                float vmax[2];
                if (kv0 + 63 <= wbase) {       // interior for both strips
#pragma unroll
                    for (int s2 = 0; s2 < 2; ++s2) {
                        const float a0 = fmaxf(fmaxf(sacc[s2][0][0], sacc[s2][0][1]), sacc[s2][0][2]);
                        const float a1 = fmaxf(fmaxf(sacc[s2][0][3], sacc[s2][1][0]), sacc[s2][1][1]);
                        const float a2 = fmaxf(fmaxf(sacc[s2][1][2], sacc[s2][1][3]), sacc[s2][2][0]);
                        const float a3 = fmaxf(fmaxf(sacc[s2][2][1], sacc[s2][2][2]), sacc[s2][2][3]);
                        const float a4 = fmaxf(fmaxf(sacc[s2][3][0], sacc[s2][3][1]), sacc[s2][3][2]);
                        const float b0 = fmaxf(fmaxf(a0, a1), a2);
                        const float b1 = fmaxf(fmaxf(a3, a4), sacc[s2][3][3]);
                        vmax[s2] = fmaxf(b0, b1);
                    }
                } else {
#pragma unroll
                    for (int s2 = 0; s2 < 2; ++s2) {
                        vmax[s2] = NEGINF;
                        const int qrow = wbase + s2 * 16 + lc;
#pragma unroll
                        for (int kt = 0; kt < 4; ++kt)
#pragma unroll
                            for (int r = 0; r < 4; ++r) {
                                const int key = kv0 + 16 * kt + 4 * lg + r;
                                float sv = (key <= qrow) ? sacc[s2][kt][r] : NEGINF;
                                sacc[s2][kt][r] = sv;
                                vmax[s2] = fmaxf(vmax[s2], sv);
                            }
                    }
                }

#pragma unroll
                for (int s2 = 0; s2 < 2; ++s2) {
                    if (__any(vmax[s2] > mreg[s2] + DEFER_THR)) {
                        float rmax = fmaxf(vmax[s2], __shfl_xor(vmax[s2], 16, 64));
                        rmax = fmaxf(rmax, __shfl_xor(rmax, 32, 64));
                        const float mnew  = fmaxf(mreg[s2], rmax);
                        const float alpha = __builtin_amdgcn_exp2f(mreg[s2] - mnew);
                        mreg[s2] = mnew;
#pragma unroll
                        for (int r = 0; r < 4; ++r) {
                            const float ar = __shfl(alpha, 4 * lg + r, 64);
                            lacc[s2][r] *= ar;
#pragma unroll
                            for (int dt = 0; dt < 8; ++dt) o[s2][dt][r] *= ar;
                        }
                    }
#pragma unroll
                    for (int kt = 0; kt < 4; ++kt)
#pragma unroll
                        for (int r = 0; r < 4; ++r)
                            sacc[s2][kt][r] = __builtin_amdgcn_exp2f(sacc[s2][kt][r] - mreg[s2]);
#pragma unroll
                    for (int u = 0; u < 2; ++u)
                        pa[s2][u] = pack8(sacc[s2][2 * u], sacc[s2][2 * u + 1]);
                    lacc[s2] = __builtin_amdgcn_mfma_f32_16x16x32_f16(pa[s2][0], vones, lacc[s2], 0, 0, 0);
                    lacc[s2] = __builtin_amdgcn_mfma_f32_16x16x32_f16(pa[s2][1], vones, lacc[s2], 0, 0, 0);
                }
            }

            if (wt < nkv) write_tile(wt & 3);
            if (lt < nkv) load_tile(lt);

            if (doc) {
                const h16* Vfb = &Vt[cb][vfoff];
#pragma unroll
                for (int dt = 0; dt < 8; ++dt) {
#pragma unroll
                    for (int u = 0; u < 2; ++u) {
                        union { h16x8 v8; h16x4 v4[2]; } bv;
                        bv.v4[0] = *(const h16x4*)(Vfb + dt * 16 * VPAD + 32 * u);
                        bv.v4[1] = *(const h16x4*)(Vfb + dt * 16 * VPAD + 32 * u + 16);
                        o[0][dt] = __builtin_amdgcn_mfma_f32_16x16x32_f16(pa[0][u], bv.v8, o[0][dt], 0, 0, 0);
                        o[1][dt] = __builtin_amdgcn_mfma_f32_16x16x32_f16(pa[1][u], bv.v8, o[1][dt], 0, 0, 0);
                    }
                }
            }
        };

        // ---- prologue: bufs 0,1 written; tile 2 in regs
        load_tile(0);
        barrier_lgkm();   // previous half's LDS reads fully done before overwrite
        write_tile(0);
        load_tile(1);
        write_tile(1);    // waits t1 loads (once per half)
        load_tile(2);     // nkv >= 4 always
        barrier_lgkm();   // bufs 0,1 visible; t2 loads in flight

        // ---- main loop: ONE barrier per TWO tiles
        for (int t = 0; t < nkv; t += 2) {
            tile_iter(t,     t + 2, t + 3);
            tile_iter(t + 1, t + 3, t + 4);
            barrier_lgkm();
        }

        // ---- epilogue: lacc[s2][r] is the full row-sum for q = wbase+16s2+4lg+r
#pragma unroll
        for (int s2 = 0; s2 < 2; ++s2) {
#pragma unroll
            for (int r = 0; r < 4; ++r) {
                const float inv = 1.0f / lacc[s2][r];
                const int qrow  = wbase + s2 * 16 + 4 * lg + r;
                float* op = Out + (size_t)qrow * RSTRIDE + bhoff + lc;
#pragma unroll
                for (int dt = 0; dt < 8; ++dt) op[dt * 16] = o[s2][dt][r] * inv;
            }
        }
    } // half
}

extern "C" void kernel_launch(void* const* d_in, const int* in_sizes, int n_in,
                              void* d_out, int out_size, void* d_ws, size_t ws_size,
                              hipStream_t stream) {
    (void)in_sizes; (void)n_in; (void)out_size; (void)d_ws; (void)ws_size;
    const float* Q = (const float*)d_in[0];
    const float* K = (const float*)d_in[1];
    const float* V = (const float*)d_in[2];
    float* O = (float*)d_out;
    fa_fwd_kernel<<<dim3(NQT / 2, 64), 512, 0, stream>>>(Q, K, V, O);
}